// Round 14
// baseline (139.201 us; speedup 1.0000x reference)
//
#include <hip/hip_runtime.h>
#include <hip/hip_bf16.h>
#include <stdint.h>

// ReplicatorDerivLayer on MI355X — factorized causal pipeline, engine v7:
// templated tile width NB (NB=4: 128x256, NB=2: 128x128), BK=32, 3-deep LDS
// (72KB -> 2 blocks/CU), one barrier per K-tile, counted vmcnt, paired-row
// XOR swizzle. This round: D2 Gc jobs paired (j, j+4) into two-segment
// blocks -> 384 uniform blocks = ONE scheduling round (was 640 -> 2 rounds).
//
//  prep: x f32 -> xb bf16 [b][e][s] + xbT bf16 [b][s][e]; Wcat=[W1^T;W2] bf16
//  D1: Fcat[s][0:512]=F1T, [512:1024]=F2T;  F2n[r][t] natural layout
//  D2: Sd[b][i] = masked diag Gram (p0 128x128 + p1 128x256);  Gc[b][j] paired
//  D3: Gp[b][i-1] = sum_{j<i} Gc[b][j]
//  D4: fitb[e, blk i half n2] = Gp_i.F1T^T + xb.Sd^T (K-capped), fused pipe
//  D5: avg = sum_s x*fit; out = relu(x*(1+fit-avg))

#define SEQ 2048
#define EMB 512
#define NBATCH 8

typedef unsigned short u16;
typedef __bf16 bf16x8 __attribute__((ext_vector_type(8)));
typedef float f32x4 __attribute__((ext_vector_type(4)));
typedef u16 u16x8 __attribute__((ext_vector_type(8)));

#define AS1 __attribute__((address_space(1)))
#define AS3 __attribute__((address_space(3)))

#define SBAR do { __builtin_amdgcn_sched_barrier(0); __builtin_amdgcn_s_barrier(); \
                  __builtin_amdgcn_sched_barrier(0); } while (0)
#define LGKM0 do { asm volatile("s_waitcnt lgkmcnt(0)" ::: "memory"); \
                   __builtin_amdgcn_sched_barrier(0); } while (0)
#define VMC(n) asm volatile("s_waitcnt vmcnt(" #n ")" ::: "memory")

__device__ __forceinline__ u16 f2bf(float f) {
  uint32_t u = __builtin_bit_cast(uint32_t, f);
  uint32_t r = u + 0x7FFFu + ((u >> 16) & 1u);
  return (u16)(r >> 16);
}
__device__ __forceinline__ float bf2f(u16 u) {
  return __builtin_bit_cast(float, (uint32_t)u << 16);
}
__device__ __forceinline__ void gld_lds16(const void* g, void* l) {
  __builtin_amdgcn_global_load_lds((AS1 uint32_t*)g, (AS3 uint32_t*)l, 16, 0, 0);
}

// ---------------- merged prep: x -> xb/xbT (z<8); W1^T (z==8); W2 (z==9) ----------------
__global__ __launch_bounds__(256) void prep_kernel(const float* __restrict__ x,
    const float* __restrict__ W1, const float* __restrict__ W2,
    u16* __restrict__ xb, u16* __restrict__ xbT, u16* __restrict__ Wcat) {
  __shared__ float tile[64][65];
  const int tid = threadIdx.x;
  const int z = blockIdx.z;
  if (z < 8) {
    const int b = z;
    const int s0 = blockIdx.x * 64, e0 = blockIdx.y * 64;
    const float* xin = x + (size_t)b * EMB * SEQ;
    #pragma unroll
    for (int it = 0; it < 4; ++it) {
      int idx = it * 256 + tid;
      int r = idx >> 4, c4 = idx & 15;
      float4 v = *(const float4*)(xin + (size_t)(e0 + r) * SEQ + s0 + c4 * 4);
      tile[r][c4 * 4 + 0] = v.x; tile[r][c4 * 4 + 1] = v.y;
      tile[r][c4 * 4 + 2] = v.z; tile[r][c4 * 4 + 3] = v.w;
    }
    __syncthreads();
    u16* ob = xb + (size_t)b * EMB * SEQ;
    #pragma unroll
    for (int it = 0; it < 2; ++it) {
      int idx = it * 256 + tid; int r = idx >> 3, c8 = idx & 7;
      u16x8 o;
      #pragma unroll
      for (int q = 0; q < 8; ++q) o[q] = f2bf(tile[r][c8 * 8 + q]);
      *(u16x8*)(ob + (size_t)(e0 + r) * SEQ + s0 + c8 * 8) = o;
    }
    u16* obT = xbT + (size_t)b * SEQ * EMB;
    #pragma unroll
    for (int it = 0; it < 2; ++it) {
      int idx = it * 256 + tid; int r = idx >> 3, c8 = idx & 7;
      u16x8 o;
      #pragma unroll
      for (int q = 0; q < 8; ++q) o[q] = f2bf(tile[c8 * 8 + q][r]);
      *(u16x8*)(obT + (size_t)(s0 + r) * EMB + e0 + c8 * 8) = o;
    }
  } else {
    const int idx = blockIdx.y * 32 + blockIdx.x;   // 0..255
    const int c0 = (idx & 15) * 32, r0 = (idx >> 4) * 32;
    const int tx = tid & 31, ty = tid >> 5;          // (32, 8)
    if (z == 8) {  // W1^T -> Wcat rows 0..511
      #pragma unroll
      for (int i = 0; i < 32; i += 8)
        tile[ty + i][tx] = W1[(size_t)(r0 + ty + i) * EMB + c0 + tx];
      __syncthreads();
      #pragma unroll
      for (int i = 0; i < 32; i += 8)
        Wcat[(size_t)(c0 + ty + i) * EMB + r0 + tx] = f2bf(tile[tx][ty + i]);
    } else {       // W2 cast -> Wcat rows 512..1023
      u16* W2b = Wcat + (size_t)512 * 512;
      #pragma unroll
      for (int i = 0; i < 32; i += 8)
        W2b[(size_t)(r0 + ty + i) * EMB + c0 + tx] =
            f2bf(W2[(size_t)(r0 + ty + i) * EMB + c0 + tx]);
    }
  }
}

// ---------------- engine v7: 128 x (64*NB) tile, BK=32, 3-deep ----------------
struct Smem {
  __align__(16) u16 A[3][4096];   // 128 rows x 32 cols bf16 (8KB)
  __align__(16) u16 B[3][8192];   // up to 256 rows x 32 cols (16KB; NB2 uses 8KB)
};

// par(t, ab, g, ld, k): operand source for K-tile t (32 cols), ab: 0=A, 1=B.
template<int NB, typename PAR>
__device__ __forceinline__ void gemm_pipe(PAR par, int nk, Smem& sm, f32x4 (&acc)[4][NB]) {
  const int tid = threadIdx.x, lane = tid & 63, wave = tid >> 6;
  const int wr = wave >> 2, wc = wave & 3;      // 2 x 4 waves; per-wave 64 x 16*NB
  const int ar = lane & 15, asel = lane >> 4;

  // LDS: line L (128B) holds rows 2L,2L+1 (4 chunks each);
  // chunk pos within line = ((row&1)*4 | colchunk) ^ (L&7) -> b128 reads conflict-light.
  auto stage = [&](int t) {
    const u16 *ga, *gb; int lda, ldb, ka, kb;
    par(t, 0, ga, lda, ka);
    par(t, 1, gb, ldb, kb);
    u16* LA = sm.A[t % 3];
    u16* LB = sm.B[t % 3];
    {
      int line = tid >> 3, cp = (tid & 7) ^ (line & 7);
      int row = line * 2 + (cp >> 2), cc = cp & 3;
      gld_lds16(ga + (size_t)row * lda + ka + cc * 8, LA + (size_t)(wave * 64) * 8);
    }
    #pragma unroll
    for (int p = 0; p < NB / 2; ++p) {
      int idx = p * 512 + tid;
      int line = idx >> 3, cp = (idx & 7) ^ (line & 7);
      int row = line * 2 + (cp >> 2), cc = cp & 3;
      gld_lds16(gb + (size_t)row * ldb + kb + cc * 8, LB + (size_t)(p * 512 + wave * 64) * 8);
    }
  };
  auto ldfrag = [&](const u16* base, int rloc) -> bf16x8 {
    int line = rloc >> 1;
    int ch = line * 8 + ((((rloc & 1) << 2) | asel) ^ (line & 7));
    return *reinterpret_cast<const bf16x8*>(base + (size_t)ch * 8);
  };

  stage(0);
  if (nk > 1) stage(1);
  if (nk > 1) { if constexpr (NB == 4) { VMC(3); } else { VMC(2); } }
  else        { VMC(0); }
  SBAR;

  for (int t = 0; t < nk; ++t) {
    const u16* A = sm.A[t % 3];
    const u16* B = sm.B[t % 3];
    bf16x8 af[4], bf[NB];
    #pragma unroll
    for (int m = 0; m < 4; ++m) af[m] = ldfrag(A, wr * 64 + m * 16 + ar);
    #pragma unroll
    for (int n = 0; n < NB; ++n) bf[n] = ldfrag(B, wc * (16 * NB) + n * 16 + ar);
    // stage(t+2) targets buf[(t-1)%3]: all waves' reads of it drained before
    // the barrier that ended tile t-1 (LGKM0 precedes that barrier) -> WAR-safe.
    if (t + 2 < nk) stage(t + 2);
    LGKM0;
    __builtin_amdgcn_s_setprio(1);
    #pragma unroll
    for (int m = 0; m < 4; ++m)
      #pragma unroll
      for (int n = 0; n < NB; ++n)
        acc[m][n] = __builtin_amdgcn_mfma_f32_16x16x32_bf16(af[m], bf[n], acc[m][n], 0, 0, 0);
    __builtin_amdgcn_s_setprio(0);
    if (t + 1 < nk) {
      if (t + 2 < nk) { if constexpr (NB == 4) { VMC(3); } else { VMC(2); } }
      else            { VMC(0); }
    }
    SBAR;
  }
}

// ---------------- GEMM kernels ----------------
// MODE 0 grid (96,1,8): id<64 -> Fcat (m=id&15, n=id>>4) [NB4];
//                       id>=64 -> F2n (id2: m2=id2>>3, n2=id2&7) [NB4]
// MODE 1 grid (384,1,1) flat, uniform ~16-tile blocks (one scheduling round):
//   id<64 -> Sd p0 (b=id>>3, i=id&7) [NB2, 16t];
//   id<128 -> Sd p1 (b=(id-64)>>3, i=(id-64)&7) [NB4, 16t];
//   id>=128 -> Gc paired (id2=id-128: j0=id2&3 then j0+4, b=(id2>>2)&7,
//              sub=id2>>5 -> m=sub>>1, n=sub&1) [NB4, 2 x 8t segments]
// MODE 2 grid (64,1,8): fitb (i=id&7, m=(id>>3)&3, n2=id>>5) [NB2, K-capped diag]
template<int MODE>
__global__ __launch_bounds__(512, 4) void k_gemm(
    const u16* __restrict__ X1, const u16* __restrict__ X2,
    const u16* __restrict__ X3, const u16* __restrict__ X4,
    u16* __restrict__ O16, u16* __restrict__ O16b) {
  __shared__ Smem sm;
  const int tid  = threadIdx.x;
  const int lane = tid & 63;
  const int wave = tid >> 6;
  const int wr = wave >> 2;
  const int wc = wave & 3;
  const int bz = blockIdx.z;
  const int id = blockIdx.x;

  const int r0 = (lane >> 4) * 4;
  const int cn = lane & 15;

  if (MODE == 0) {
    const u16 *Ap, *Bp;
    int m = 0, n = 0, m2 = 0, n2 = 0;
    if (id < 64) {     // Fcat
      m = id & 15; n = id >> 4;
      Ap = X1 + (size_t)bz * SEQ * EMB + (size_t)(m * 128) * 512;
      Bp = X2 + (size_t)(n * 256) * 512;
    } else {           // F2n
      int id2 = id - 64; m2 = id2 >> 3; n2 = id2 & 7;
      Ap = X2 + (size_t)512 * 512 + (size_t)(m2 * 128) * 512;
      Bp = X1 + (size_t)bz * SEQ * EMB + (size_t)(n2 * 256) * 512;
    }
    auto par = [&](int t, int ab, const u16*& gp, int& ld, int& k) {
      gp = ab ? Bp : Ap; ld = 512; k = t * 32;
    };
    f32x4 acc[4][4];
    #pragma unroll
    for (int i = 0; i < 4; ++i)
      #pragma unroll
      for (int j = 0; j < 4; ++j) acc[i][j] = (f32x4){0.f, 0.f, 0.f, 0.f};
    gemm_pipe<4>(par, 16, sm, acc);
    if (id < 64) {
      u16* C = O16 + (size_t)bz * SEQ * 1024;
      #pragma unroll
      for (int mm = 0; mm < 4; ++mm)
        #pragma unroll
        for (int nn = 0; nn < 4; ++nn)
          #pragma unroll
          for (int r = 0; r < 4; ++r) {
            int lr = wr * 64 + mm * 16 + r0 + r, lc = wc * 64 + nn * 16 + cn;
            C[(size_t)(m * 128 + lr) * 1024 + n * 256 + lc] = f2bf(acc[mm][nn][r]);
          }
    } else {
      u16* C = O16b + (size_t)bz * EMB * SEQ;
      #pragma unroll
      for (int mm = 0; mm < 4; ++mm)
        #pragma unroll
        for (int nn = 0; nn < 4; ++nn)
          #pragma unroll
          for (int r = 0; r < 4; ++r) {
            int lr = wr * 64 + mm * 16 + r0 + r, lc = wc * 64 + nn * 16 + cn;
            C[(size_t)(m2 * 128 + lr) * SEQ + n2 * 256 + lc] = f2bf(acc[mm][nn][r]);
          }
    }
  } else if (MODE == 1) {
    if (id < 64) {     // Sd p0: 128x128 lower quadrant, NB2, K=512
      const int b = id >> 3, i = id & 7;
      const u16* Fb = X1 + (size_t)b * SEQ * 1024;
      const u16* Ap = Fb + (size_t)(i * 256) * 1024;
      const u16* Bp = Fb + 512 + (size_t)(i * 256) * 1024;
      auto par = [&](int t, int ab, const u16*& gp, int& ld, int& k) {
        gp = ab ? Bp : Ap; ld = 1024; k = t * 32;
      };
      f32x4 acc[4][2];
      #pragma unroll
      for (int a = 0; a < 4; ++a)
        #pragma unroll
        for (int c = 0; c < 2; ++c) acc[a][c] = (f32x4){0.f, 0.f, 0.f, 0.f};
      gemm_pipe<2>(par, 16, sm, acc);
      u16* C = O16 + (size_t)(b * 8 + i) * 256 * 256;
      #pragma unroll
      for (int mm = 0; mm < 4; ++mm)
        #pragma unroll
        for (int nn = 0; nn < 2; ++nn)
          #pragma unroll
          for (int r = 0; r < 4; ++r) {
            int lr = wr * 64 + mm * 16 + r0 + r, lc = wc * 32 + nn * 16 + cn;
            float v = (lc > lr) ? 0.f : acc[mm][nn][r];  // keep t <= s
            C[(size_t)lr * 256 + lc] = f2bf(v);
          }
    } else if (id < 128) {  // Sd p1: rows 128-255 full width, NB4, K=512
      const int id2 = id - 64, b = id2 >> 3, i = id2 & 7;
      const u16* Fb = X1 + (size_t)b * SEQ * 1024;
      const u16* Ap = Fb + (size_t)(i * 256 + 128) * 1024;
      const u16* Bp = Fb + 512 + (size_t)(i * 256) * 1024;
      auto par = [&](int t, int ab, const u16*& gp, int& ld, int& k) {
        gp = ab ? Bp : Ap; ld = 1024; k = t * 32;
      };
      f32x4 acc[4][4];
      #pragma unroll
      for (int a = 0; a < 4; ++a)
        #pragma unroll
        for (int c = 0; c < 4; ++c) acc[a][c] = (f32x4){0.f, 0.f, 0.f, 0.f};
      gemm_pipe<4>(par, 16, sm, acc);
      u16* C = O16 + (size_t)(b * 8 + i) * 256 * 256;
      #pragma unroll
      for (int mm = 0; mm < 4; ++mm)
        #pragma unroll
        for (int nn = 0; nn < 4; ++nn)
          #pragma unroll
          for (int r = 0; r < 4; ++r) {
            int lr = wr * 64 + mm * 16 + r0 + r, lc = wc * 64 + nn * 16 + cn;
            int grow = 128 + lr;
            float v = (lc > grow) ? 0.f : acc[mm][nn][r];
            C[(size_t)grow * 256 + lc] = f2bf(v);
          }
    } else {           // Gc paired (j0, j0+4): two 8-tile segments, NB4
      const int id2 = id - 128;
      const int j0 = id2 & 3, b = (id2 >> 2) & 7, sub = id2 >> 5;
      const int m = sub >> 1, n = sub & 1;
      #pragma unroll
      for (int seg = 0; seg < 2; ++seg) {
        const int j = j0 + seg * 4;
        const u16* Ap = X2 + (size_t)b * EMB * SEQ + (size_t)(m * 128) * SEQ + j * 256;
        const u16* Bp = X3 + (size_t)b * EMB * SEQ + (size_t)(n * 256) * SEQ + j * 256;
        auto par = [&](int t, int ab, const u16*& gp, int& ld, int& k) {
          gp = ab ? Bp : Ap; ld = SEQ; k = t * 32;
        };
        f32x4 acc[4][4];
        #pragma unroll
        for (int a = 0; a < 4; ++a)
          #pragma unroll
          for (int c = 0; c < 4; ++c) acc[a][c] = (f32x4){0.f, 0.f, 0.f, 0.f};
        gemm_pipe<4>(par, 8, sm, acc);
        u16* C = O16b + (size_t)(b * 8 + j) * EMB * EMB;
        #pragma unroll
        for (int mm = 0; mm < 4; ++mm)
          #pragma unroll
          for (int nn = 0; nn < 4; ++nn)
            #pragma unroll
            for (int r = 0; r < 4; ++r) {
              int lr = wr * 64 + mm * 16 + r0 + r, lc = wc * 64 + nn * 16 + cn;
              C[(size_t)(m * 128 + lr) * EMB + n * 256 + lc] = f2bf(acc[mm][nn][r]);
            }
      }
    }
  } else {
    // fitfused NB2: i = id&7 (s-block), m = (id>>3)&3 (e-quarter), n2 = id>>5 (s-half)
    // tiles 0-15: Gp_i . F1T^T (K=512); then diag: K = n2 ? 256 : 128 (t <= s cap)
    const int i = id & 7, m = (id >> 3) & 3, n2 = id >> 5;
    const u16* Agp = (i > 0) ? X1 + (size_t)(bz * 7 + i - 1) * EMB * EMB + (size_t)(m * 128) * 512
                             : X1;
    const u16* Bf1 = X2 + (size_t)bz * SEQ * 1024 + (size_t)(i * 256 + n2 * 128) * 1024;
    const u16* Axb = X3 + (size_t)bz * EMB * SEQ + (size_t)(m * 128) * SEQ;
    const u16* Bsd = X4 + (size_t)(bz * 8 + i) * 256 * 256 + (size_t)(n2 * 128) * 256;
    auto par = [&](int t, int ab, const u16*& gp, int& ld, int& k) {
      int tt = (i > 0) ? t : t + 16;
      if (tt < 16) {
        if (!ab) { gp = Agp; ld = 512;  k = tt * 32; }
        else     { gp = Bf1; ld = 1024; k = tt * 32; }
      } else {
        int u = tt - 16;
        if (!ab) { gp = Axb; ld = SEQ; k = i * 256 + u * 32; }
        else     { gp = Bsd; ld = 256; k = u * 32; }
      }
    };
    const int nkd = n2 ? 8 : 4;
    f32x4 acc[4][2];
    #pragma unroll
    for (int a = 0; a < 4; ++a)
      #pragma unroll
      for (int c = 0; c < 2; ++c) acc[a][c] = (f32x4){0.f, 0.f, 0.f, 0.f};
    gemm_pipe<2>(par, (i > 0 ? 16 : 0) + nkd, sm, acc);
    u16* C = O16 + (size_t)bz * EMB * SEQ;
    #pragma unroll
    for (int mm = 0; mm < 4; ++mm)
      #pragma unroll
      for (int nn = 0; nn < 2; ++nn)
        #pragma unroll
        for (int r = 0; r < 4; ++r) {
          int lr = wr * 64 + mm * 16 + r0 + r, lc = wc * 32 + nn * 16 + cn;
          C[(size_t)(m * 128 + lr) * SEQ + i * 256 + n2 * 128 + lc] = f2bf(acc[mm][nn][r]);
        }
  }
}

// ---------------- prefix over chunks: Gp[b][i-1] = sum_{j<i} Gc[b][j] ----------------
__global__ __launch_bounds__(256) void k_prefix(const u16* __restrict__ Gc,
                                                u16* __restrict__ Gp) {
  const int b = blockIdx.z;
  const size_t base = ((size_t)blockIdx.x * 256 + threadIdx.x) * 8;
  float run[8] = {0.f, 0.f, 0.f, 0.f, 0.f, 0.f, 0.f, 0.f};
  #pragma unroll
  for (int j = 0; j < 7; ++j) {
    u16x8 v = *(const u16x8*)(Gc + (size_t)(b * 8 + j) * EMB * EMB + base);
    u16x8 o;
    #pragma unroll
    for (int q = 0; q < 8; ++q) { run[q] += bf2f(v[q]); o[q] = f2bf(run[q]); }
    *(u16x8*)(Gp + (size_t)(b * 7 + j) * EMB * EMB + base) = o;
  }
}

// ---------------- finalize (fit in bf16) ----------------
__global__ __launch_bounds__(256) void finalize_kernel(const u16* __restrict__ xb,
    const u16* __restrict__ fitb, float* __restrict__ out) {
  const size_t row = blockIdx.x;  // b*EMB + e
  const u16* xr = xb + row * SEQ;
  const u16* fr = fitb + row * SEQ;
  float* orow = out + row * SEQ;
  const int tid = threadIdx.x;

  float xv[2][4], fv[2][4];
  float part = 0.f;
  #pragma unroll
  for (int i = 0; i < 2; ++i) {
    const int s0 = i * 1024 + tid * 4;
    ushort4 xu = *reinterpret_cast<const ushort4*>(xr + s0);
    ushort4 fu = *reinterpret_cast<const ushort4*>(fr + s0);
    xv[i][0] = bf2f(xu.x); xv[i][1] = bf2f(xu.y); xv[i][2] = bf2f(xu.z); xv[i][3] = bf2f(xu.w);
    fv[i][0] = bf2f(fu.x); fv[i][1] = bf2f(fu.y); fv[i][2] = bf2f(fu.z); fv[i][3] = bf2f(fu.w);
    part += xv[i][0] * fv[i][0] + xv[i][1] * fv[i][1] + xv[i][2] * fv[i][2] + xv[i][3] * fv[i][3];
  }
  #pragma unroll
  for (int off = 1; off < 64; off <<= 1) part += __shfl_xor(part, off);
  __shared__ float wsum[4];
  const int wave = tid >> 6, lane = tid & 63;
  if (lane == 0) wsum[wave] = part;
  __syncthreads();
  const float avg = wsum[0] + wsum[1] + wsum[2] + wsum[3];

  #pragma unroll
  for (int i = 0; i < 2; ++i) {
    float4 o;
    o.x = xv[i][0] * (1.f + fv[i][0] - avg); o.x = o.x > 0.f ? o.x : 0.f;
    o.y = xv[i][1] * (1.f + fv[i][1] - avg); o.y = o.y > 0.f ? o.y : 0.f;
    o.z = xv[i][2] * (1.f + fv[i][2] - avg); o.z = o.z > 0.f ? o.z : 0.f;
    o.w = xv[i][3] * (1.f + fv[i][3] - avg); o.w = o.w > 0.f ? o.w : 0.f;
    reinterpret_cast<float4*>(orow)[i * 256 + tid] = o;
  }
}

extern "C" void kernel_launch(void* const* d_in, const int* in_sizes, int n_in,
                              void* d_out, int out_size, void* d_ws, size_t ws_size,
                              hipStream_t stream) {
  const float* x  = (const float*)d_in[0];
  const float* W1 = (const float*)d_in[1];
  const float* W2 = (const float*)d_in[2];
  float* out = (float*)d_out;

  char* ws = (char*)d_ws;
  const size_t nX = (size_t)NBATCH * EMB * SEQ;  // 8,388,608

  size_t off = 0;
  u16* xb   = (u16*)(ws + off); off += nX * 2;                          // 16 MB
  u16* Fcat = (u16*)(ws + off); off += (size_t)NBATCH * SEQ * 1024 * 2; // 32 MB
  const size_t offOverlay = off;                                        // fitb overlays xbT
  u16* xbT  = (u16*)(ws + off); off += nX * 2;                          // 16 MB (dead after D1)
  u16* Wcat = (u16*)(ws + off); off += (size_t)1024 * 512 * 2;          // 1 MB  (dead after D1)
  u16* F2n  = (u16*)(ws + off); off += nX * 2;                          // 16 MB (dead after D2)
  u16* Sd   = (u16*)(ws + off); off += (size_t)NBATCH * 8 * 256 * 256 * 2;  // 8 MB
  u16* Gc   = (u16*)(ws + off); off += (size_t)NBATCH * 8 * EMB * EMB * 2;  // 32 MB
  u16* Gp   = (u16*)(ws + off); off += (size_t)NBATCH * 7 * EMB * EMB * 2;  // 28 MB
  u16* fitb = (u16*)(ws + offOverlay);                                  // 16 MB (over xbT)
  // total: ~149 MiB

  // prep (merged: x tiles on z<8, W1^T on z==8, W2 on z==9)
  prep_kernel<<<dim3(SEQ / 64, EMB / 64, NBATCH + 2), 256, 0, stream>>>(
      x, W1, W2, xb, xbT, Wcat);

  // D1: Fcat + F2n
  k_gemm<0><<<dim3(96, 1, NBATCH), 512, 0, stream>>>(
      xbT, Wcat, nullptr, nullptr, Fcat, F2n);

  // D2: Sd (p0 + p1) + paired Gc — 384 uniform blocks, one scheduling round
  k_gemm<1><<<dim3(384, 1, 1), 512, 0, stream>>>(
      Fcat, xb, F2n, nullptr, Sd, Gc);

  // D3: prefix-sum chunks -> Gp
  k_prefix<<<dim3(128, 1, NBATCH), 256, 0, stream>>>(Gc, Gp);

  // D4: fitfused -> fitb (bf16), 512 blocks, K-capped diagonal
  k_gemm<2><<<dim3(64, 1, NBATCH), 512, 0, stream>>>(
      Gp, Fcat, xb, Sd, fitb, nullptr);

  // D5: finalize
  finalize_kernel<<<NBATCH * EMB, 256, 0, stream>>>(xb, fitb, out);
}

// Round 15
// 114.092 us; speedup vs baseline: 1.2201x; 1.2201x over previous
//
#include <hip/hip_runtime.h>
#include <hip/hip_bf16.h>
#include <stdint.h>

// ReplicatorDerivLayer on MI355X — factorized causal pipeline, engine v7:
// templated tile width NB (NB=4: 128x256, NB=2: 128x128), BK=32, 3-deep LDS
// (72KB -> 2 blocks/CU), one barrier per K-tile, counted vmcnt, paired-row
// XOR swizzle. R14 lesson: ONE acc + ONE gemm_pipe body per kernel
// instantiation (paired two-pipe blocks spilled: VGPR 128->64, +50MB scratch).
// This is the R13 state (best measured: 114.8 us).
//
//  prep: x f32 -> xb bf16 [b][e][s] + xbT bf16 [b][s][e]; Wcat=[W1^T;W2] bf16
//  D1: Fcat[s][0:512]=F1T, [512:1024]=F2T;  F2n[r][t] natural layout
//  D2: Sd[b][i] = masked diag Gram (p0 128x128 + p1 128x256);  Gc[b][j]
//  D3: Gp[b][i-1] = sum_{j<i} Gc[b][j]
//  D4: fitb[e, blk i half n2] = Gp_i.F1T^T + xb.Sd^T (K-capped), fused pipe
//  D5: avg = sum_s x*fit; out = relu(x*(1+fit-avg))

#define SEQ 2048
#define EMB 512
#define NBATCH 8

typedef unsigned short u16;
typedef __bf16 bf16x8 __attribute__((ext_vector_type(8)));
typedef float f32x4 __attribute__((ext_vector_type(4)));
typedef u16 u16x8 __attribute__((ext_vector_type(8)));

#define AS1 __attribute__((address_space(1)))
#define AS3 __attribute__((address_space(3)))

#define SBAR do { __builtin_amdgcn_sched_barrier(0); __builtin_amdgcn_s_barrier(); \
                  __builtin_amdgcn_sched_barrier(0); } while (0)
#define LGKM0 do { asm volatile("s_waitcnt lgkmcnt(0)" ::: "memory"); \
                   __builtin_amdgcn_sched_barrier(0); } while (0)
#define VMC(n) asm volatile("s_waitcnt vmcnt(" #n ")" ::: "memory")

__device__ __forceinline__ u16 f2bf(float f) {
  uint32_t u = __builtin_bit_cast(uint32_t, f);
  uint32_t r = u + 0x7FFFu + ((u >> 16) & 1u);
  return (u16)(r >> 16);
}
__device__ __forceinline__ float bf2f(u16 u) {
  return __builtin_bit_cast(float, (uint32_t)u << 16);
}
__device__ __forceinline__ void gld_lds16(const void* g, void* l) {
  __builtin_amdgcn_global_load_lds((AS1 uint32_t*)g, (AS3 uint32_t*)l, 16, 0, 0);
}

// ---------------- merged prep: x -> xb/xbT (z<8); W1^T (z==8); W2 (z==9) ----------------
__global__ __launch_bounds__(256) void prep_kernel(const float* __restrict__ x,
    const float* __restrict__ W1, const float* __restrict__ W2,
    u16* __restrict__ xb, u16* __restrict__ xbT, u16* __restrict__ Wcat) {
  __shared__ float tile[64][65];
  const int tid = threadIdx.x;
  const int z = blockIdx.z;
  if (z < 8) {
    const int b = z;
    const int s0 = blockIdx.x * 64, e0 = blockIdx.y * 64;
    const float* xin = x + (size_t)b * EMB * SEQ;
    #pragma unroll
    for (int it = 0; it < 4; ++it) {
      int idx = it * 256 + tid;
      int r = idx >> 4, c4 = idx & 15;
      float4 v = *(const float4*)(xin + (size_t)(e0 + r) * SEQ + s0 + c4 * 4);
      tile[r][c4 * 4 + 0] = v.x; tile[r][c4 * 4 + 1] = v.y;
      tile[r][c4 * 4 + 2] = v.z; tile[r][c4 * 4 + 3] = v.w;
    }
    __syncthreads();
    u16* ob = xb + (size_t)b * EMB * SEQ;
    #pragma unroll
    for (int it = 0; it < 2; ++it) {
      int idx = it * 256 + tid; int r = idx >> 3, c8 = idx & 7;
      u16x8 o;
      #pragma unroll
      for (int q = 0; q < 8; ++q) o[q] = f2bf(tile[r][c8 * 8 + q]);
      *(u16x8*)(ob + (size_t)(e0 + r) * SEQ + s0 + c8 * 8) = o;
    }
    u16* obT = xbT + (size_t)b * SEQ * EMB;
    #pragma unroll
    for (int it = 0; it < 2; ++it) {
      int idx = it * 256 + tid; int r = idx >> 3, c8 = idx & 7;
      u16x8 o;
      #pragma unroll
      for (int q = 0; q < 8; ++q) o[q] = f2bf(tile[c8 * 8 + q][r]);
      *(u16x8*)(obT + (size_t)(s0 + r) * EMB + e0 + c8 * 8) = o;
    }
  } else {
    const int idx = blockIdx.y * 32 + blockIdx.x;   // 0..255
    const int c0 = (idx & 15) * 32, r0 = (idx >> 4) * 32;
    const int tx = tid & 31, ty = tid >> 5;          // (32, 8)
    if (z == 8) {  // W1^T -> Wcat rows 0..511
      #pragma unroll
      for (int i = 0; i < 32; i += 8)
        tile[ty + i][tx] = W1[(size_t)(r0 + ty + i) * EMB + c0 + tx];
      __syncthreads();
      #pragma unroll
      for (int i = 0; i < 32; i += 8)
        Wcat[(size_t)(c0 + ty + i) * EMB + r0 + tx] = f2bf(tile[tx][ty + i]);
    } else {       // W2 cast -> Wcat rows 512..1023
      u16* W2b = Wcat + (size_t)512 * 512;
      #pragma unroll
      for (int i = 0; i < 32; i += 8)
        W2b[(size_t)(r0 + ty + i) * EMB + c0 + tx] =
            f2bf(W2[(size_t)(r0 + ty + i) * EMB + c0 + tx]);
    }
  }
}

// ---------------- engine v7: 128 x (64*NB) tile, BK=32, 3-deep ----------------
struct Smem {
  __align__(16) u16 A[3][4096];   // 128 rows x 32 cols bf16 (8KB)
  __align__(16) u16 B[3][8192];   // up to 256 rows x 32 cols (16KB; NB2 uses 8KB)
};

// par(t, ab, g, ld, k): operand source for K-tile t (32 cols), ab: 0=A, 1=B.
template<int NB, typename PAR>
__device__ __forceinline__ void gemm_pipe(PAR par, int nk, Smem& sm, f32x4 (&acc)[4][NB]) {
  const int tid = threadIdx.x, lane = tid & 63, wave = tid >> 6;
  const int wr = wave >> 2, wc = wave & 3;      // 2 x 4 waves; per-wave 64 x 16*NB
  const int ar = lane & 15, asel = lane >> 4;

  // LDS: line L (128B) holds rows 2L,2L+1 (4 chunks each);
  // chunk pos within line = ((row&1)*4 | colchunk) ^ (L&7) -> b128 reads conflict-light.
  auto stage = [&](int t) {
    const u16 *ga, *gb; int lda, ldb, ka, kb;
    par(t, 0, ga, lda, ka);
    par(t, 1, gb, ldb, kb);
    u16* LA = sm.A[t % 3];
    u16* LB = sm.B[t % 3];
    {
      int line = tid >> 3, cp = (tid & 7) ^ (line & 7);
      int row = line * 2 + (cp >> 2), cc = cp & 3;
      gld_lds16(ga + (size_t)row * lda + ka + cc * 8, LA + (size_t)(wave * 64) * 8);
    }
    #pragma unroll
    for (int p = 0; p < NB / 2; ++p) {
      int idx = p * 512 + tid;
      int line = idx >> 3, cp = (idx & 7) ^ (line & 7);
      int row = line * 2 + (cp >> 2), cc = cp & 3;
      gld_lds16(gb + (size_t)row * ldb + kb + cc * 8, LB + (size_t)(p * 512 + wave * 64) * 8);
    }
  };
  auto ldfrag = [&](const u16* base, int rloc) -> bf16x8 {
    int line = rloc >> 1;
    int ch = line * 8 + ((((rloc & 1) << 2) | asel) ^ (line & 7));
    return *reinterpret_cast<const bf16x8*>(base + (size_t)ch * 8);
  };

  stage(0);
  if (nk > 1) stage(1);
  if (nk > 1) { if constexpr (NB == 4) { VMC(3); } else { VMC(2); } }
  else        { VMC(0); }
  SBAR;

  for (int t = 0; t < nk; ++t) {
    const u16* A = sm.A[t % 3];
    const u16* B = sm.B[t % 3];
    bf16x8 af[4], bf[NB];
    #pragma unroll
    for (int m = 0; m < 4; ++m) af[m] = ldfrag(A, wr * 64 + m * 16 + ar);
    #pragma unroll
    for (int n = 0; n < NB; ++n) bf[n] = ldfrag(B, wc * (16 * NB) + n * 16 + ar);
    // stage(t+2) targets buf[(t-1)%3]: all waves' reads of it drained before
    // the barrier that ended tile t-1 (LGKM0 precedes that barrier) -> WAR-safe.
    if (t + 2 < nk) stage(t + 2);
    LGKM0;
    __builtin_amdgcn_s_setprio(1);
    #pragma unroll
    for (int m = 0; m < 4; ++m)
      #pragma unroll
      for (int n = 0; n < NB; ++n)
        acc[m][n] = __builtin_amdgcn_mfma_f32_16x16x32_bf16(af[m], bf[n], acc[m][n], 0, 0, 0);
    __builtin_amdgcn_s_setprio(0);
    if (t + 1 < nk) {
      if (t + 2 < nk) { if constexpr (NB == 4) { VMC(3); } else { VMC(2); } }
      else            { VMC(0); }
    }
    SBAR;
  }
}

// ---------------- GEMM kernels ----------------
// MODE 0 grid (96,1,8): id<64 -> Fcat (m=id&15, n=id>>4) [NB4];
//                       id>=64 -> F2n (id2: m2=id2>>3, n2=id2&7) [NB4]
// MODE 1 grid (640,1,1) flat, Sd first so the 128-block tail round is all
//   short Gc blocks: id<64 -> Sd p0 (b=id>>3, i=id&7) [NB2];
//   id<128 -> Sd p1 (b=(id-64)>>3, i=(id-64)&7) [NB4];
//   id>=128 -> Gc (id2=id-128: j=id2&7, b=(id2>>3)&7, sub=id2>>6) [NB4, 8 tiles]
// MODE 2 grid (64,1,8): fitb (i=id&7, m=(id>>3)&3, n2=id>>5) [NB2, K-capped diag]
template<int MODE>
__global__ __launch_bounds__(512, 4) void k_gemm(
    const u16* __restrict__ X1, const u16* __restrict__ X2,
    const u16* __restrict__ X3, const u16* __restrict__ X4,
    u16* __restrict__ O16, u16* __restrict__ O16b) {
  __shared__ Smem sm;
  const int tid  = threadIdx.x;
  const int lane = tid & 63;
  const int wave = tid >> 6;
  const int wr = wave >> 2;
  const int wc = wave & 3;
  const int bz = blockIdx.z;
  const int id = blockIdx.x;

  const int r0 = (lane >> 4) * 4;
  const int cn = lane & 15;

  if (MODE == 0) {
    const u16 *Ap, *Bp;
    int m = 0, n = 0, m2 = 0, n2 = 0;
    if (id < 64) {     // Fcat
      m = id & 15; n = id >> 4;
      Ap = X1 + (size_t)bz * SEQ * EMB + (size_t)(m * 128) * 512;
      Bp = X2 + (size_t)(n * 256) * 512;
    } else {           // F2n
      int id2 = id - 64; m2 = id2 >> 3; n2 = id2 & 7;
      Ap = X2 + (size_t)512 * 512 + (size_t)(m2 * 128) * 512;
      Bp = X1 + (size_t)bz * SEQ * EMB + (size_t)(n2 * 256) * 512;
    }
    auto par = [&](int t, int ab, const u16*& gp, int& ld, int& k) {
      gp = ab ? Bp : Ap; ld = 512; k = t * 32;
    };
    f32x4 acc[4][4];
    #pragma unroll
    for (int i = 0; i < 4; ++i)
      #pragma unroll
      for (int j = 0; j < 4; ++j) acc[i][j] = (f32x4){0.f, 0.f, 0.f, 0.f};
    gemm_pipe<4>(par, 16, sm, acc);
    if (id < 64) {
      u16* C = O16 + (size_t)bz * SEQ * 1024;
      #pragma unroll
      for (int mm = 0; mm < 4; ++mm)
        #pragma unroll
        for (int nn = 0; nn < 4; ++nn)
          #pragma unroll
          for (int r = 0; r < 4; ++r) {
            int lr = wr * 64 + mm * 16 + r0 + r, lc = wc * 64 + nn * 16 + cn;
            C[(size_t)(m * 128 + lr) * 1024 + n * 256 + lc] = f2bf(acc[mm][nn][r]);
          }
    } else {
      u16* C = O16b + (size_t)bz * EMB * SEQ;
      #pragma unroll
      for (int mm = 0; mm < 4; ++mm)
        #pragma unroll
        for (int nn = 0; nn < 4; ++nn)
          #pragma unroll
          for (int r = 0; r < 4; ++r) {
            int lr = wr * 64 + mm * 16 + r0 + r, lc = wc * 64 + nn * 16 + cn;
            C[(size_t)(m2 * 128 + lr) * SEQ + n2 * 256 + lc] = f2bf(acc[mm][nn][r]);
          }
    }
  } else if (MODE == 1) {
    if (id < 64) {     // Sd p0: 128x128 lower quadrant, NB2, K=512
      const int b = id >> 3, i = id & 7;
      const u16* Fb = X1 + (size_t)b * SEQ * 1024;
      const u16* Ap = Fb + (size_t)(i * 256) * 1024;
      const u16* Bp = Fb + 512 + (size_t)(i * 256) * 1024;
      auto par = [&](int t, int ab, const u16*& gp, int& ld, int& k) {
        gp = ab ? Bp : Ap; ld = 1024; k = t * 32;
      };
      f32x4 acc[4][2];
      #pragma unroll
      for (int a = 0; a < 4; ++a)
        #pragma unroll
        for (int c = 0; c < 2; ++c) acc[a][c] = (f32x4){0.f, 0.f, 0.f, 0.f};
      gemm_pipe<2>(par, 16, sm, acc);
      u16* C = O16 + (size_t)(b * 8 + i) * 256 * 256;
      #pragma unroll
      for (int mm = 0; mm < 4; ++mm)
        #pragma unroll
        for (int nn = 0; nn < 2; ++nn)
          #pragma unroll
          for (int r = 0; r < 4; ++r) {
            int lr = wr * 64 + mm * 16 + r0 + r, lc = wc * 32 + nn * 16 + cn;
            float v = (lc > lr) ? 0.f : acc[mm][nn][r];  // keep t <= s
            C[(size_t)lr * 256 + lc] = f2bf(v);
          }
    } else if (id < 128) {  // Sd p1: rows 128-255 full width, NB4, K=512
      const int id2 = id - 64, b = id2 >> 3, i = id2 & 7;
      const u16* Fb = X1 + (size_t)b * SEQ * 1024;
      const u16* Ap = Fb + (size_t)(i * 256 + 128) * 1024;
      const u16* Bp = Fb + 512 + (size_t)(i * 256) * 1024;
      auto par = [&](int t, int ab, const u16*& gp, int& ld, int& k) {
        gp = ab ? Bp : Ap; ld = 1024; k = t * 32;
      };
      f32x4 acc[4][4];
      #pragma unroll
      for (int a = 0; a < 4; ++a)
        #pragma unroll
        for (int c = 0; c < 4; ++c) acc[a][c] = (f32x4){0.f, 0.f, 0.f, 0.f};
      gemm_pipe<4>(par, 16, sm, acc);
      u16* C = O16 + (size_t)(b * 8 + i) * 256 * 256;
      #pragma unroll
      for (int mm = 0; mm < 4; ++mm)
        #pragma unroll
        for (int nn = 0; nn < 4; ++nn)
          #pragma unroll
          for (int r = 0; r < 4; ++r) {
            int lr = wr * 64 + mm * 16 + r0 + r, lc = wc * 64 + nn * 16 + cn;
            int grow = 128 + lr;
            float v = (lc > grow) ? 0.f : acc[mm][nn][r];
            C[(size_t)grow * 256 + lc] = f2bf(v);
          }
    } else {           // Gc (j; m,n): NB4, K=256 (short: fills the tail round)
      const int id2 = id - 128;
      const int j = id2 & 7, b = (id2 >> 3) & 7, sub = id2 >> 6;
      const int m = sub >> 1, n = sub & 1;
      const u16* Ap = X2 + (size_t)b * EMB * SEQ + (size_t)(m * 128) * SEQ + j * 256;
      const u16* Bp = X3 + (size_t)b * EMB * SEQ + (size_t)(n * 256) * SEQ + j * 256;
      auto par = [&](int t, int ab, const u16*& gp, int& ld, int& k) {
        gp = ab ? Bp : Ap; ld = SEQ; k = t * 32;
      };
      f32x4 acc[4][4];
      #pragma unroll
      for (int a = 0; a < 4; ++a)
        #pragma unroll
        for (int c = 0; c < 4; ++c) acc[a][c] = (f32x4){0.f, 0.f, 0.f, 0.f};
      gemm_pipe<4>(par, 8, sm, acc);
      u16* C = O16b + (size_t)(b * 8 + j) * EMB * EMB;
      #pragma unroll
      for (int mm = 0; mm < 4; ++mm)
        #pragma unroll
        for (int nn = 0; nn < 4; ++nn)
          #pragma unroll
          for (int r = 0; r < 4; ++r) {
            int lr = wr * 64 + mm * 16 + r0 + r, lc = wc * 64 + nn * 16 + cn;
            C[(size_t)(m * 128 + lr) * EMB + n * 256 + lc] = f2bf(acc[mm][nn][r]);
          }
    }
  } else {
    // fitfused NB2: i = id&7 (s-block), m = (id>>3)&3 (e-quarter), n2 = id>>5 (s-half)
    // tiles 0-15: Gp_i . F1T^T (K=512); then diag: K = n2 ? 256 : 128 (t <= s cap)
    const int i = id & 7, m = (id >> 3) & 3, n2 = id >> 5;
    const u16* Agp = (i > 0) ? X1 + (size_t)(bz * 7 + i - 1) * EMB * EMB + (size_t)(m * 128) * 512
                             : X1;
    const u16* Bf1 = X2 + (size_t)bz * SEQ * 1024 + (size_t)(i * 256 + n2 * 128) * 1024;
    const u16* Axb = X3 + (size_t)bz * EMB * SEQ + (size_t)(m * 128) * SEQ;
    const u16* Bsd = X4 + (size_t)(bz * 8 + i) * 256 * 256 + (size_t)(n2 * 128) * 256;
    auto par = [&](int t, int ab, const u16*& gp, int& ld, int& k) {
      int tt = (i > 0) ? t : t + 16;
      if (tt < 16) {
        if (!ab) { gp = Agp; ld = 512;  k = tt * 32; }
        else     { gp = Bf1; ld = 1024; k = tt * 32; }
      } else {
        int u = tt - 16;
        if (!ab) { gp = Axb; ld = SEQ; k = i * 256 + u * 32; }
        else     { gp = Bsd; ld = 256; k = u * 32; }
      }
    };
    const int nkd = n2 ? 8 : 4;
    f32x4 acc[4][2];
    #pragma unroll
    for (int a = 0; a < 4; ++a)
      #pragma unroll
      for (int c = 0; c < 2; ++c) acc[a][c] = (f32x4){0.f, 0.f, 0.f, 0.f};
    gemm_pipe<2>(par, (i > 0 ? 16 : 0) + nkd, sm, acc);
    u16* C = O16 + (size_t)bz * EMB * SEQ;
    #pragma unroll
    for (int mm = 0; mm < 4; ++mm)
      #pragma unroll
      for (int nn = 0; nn < 2; ++nn)
        #pragma unroll
        for (int r = 0; r < 4; ++r) {
          int lr = wr * 64 + mm * 16 + r0 + r, lc = wc * 32 + nn * 16 + cn;
          C[(size_t)(m * 128 + lr) * SEQ + i * 256 + n2 * 128 + lc] = f2bf(acc[mm][nn][r]);
        }
  }
}

// ---------------- prefix over chunks: Gp[b][i-1] = sum_{j<i} Gc[b][j] ----------------
__global__ __launch_bounds__(256) void k_prefix(const u16* __restrict__ Gc,
                                                u16* __restrict__ Gp) {
  const int b = blockIdx.z;
  const size_t base = ((size_t)blockIdx.x * 256 + threadIdx.x) * 8;
  float run[8] = {0.f, 0.f, 0.f, 0.f, 0.f, 0.f, 0.f, 0.f};
  #pragma unroll
  for (int j = 0; j < 7; ++j) {
    u16x8 v = *(const u16x8*)(Gc + (size_t)(b * 8 + j) * EMB * EMB + base);
    u16x8 o;
    #pragma unroll
    for (int q = 0; q < 8; ++q) { run[q] += bf2f(v[q]); o[q] = f2bf(run[q]); }
    *(u16x8*)(Gp + (size_t)(b * 7 + j) * EMB * EMB + base) = o;
  }
}

// ---------------- finalize (fit in bf16) ----------------
__global__ __launch_bounds__(256) void finalize_kernel(const u16* __restrict__ xb,
    const u16* __restrict__ fitb, float* __restrict__ out) {
  const size_t row = blockIdx.x;  // b*EMB + e
  const u16* xr = xb + row * SEQ;
  const u16* fr = fitb + row * SEQ;
  float* orow = out + row * SEQ;
  const int tid = threadIdx.x;

  float xv[2][4], fv[2][4];
  float part = 0.f;
  #pragma unroll
  for (int i = 0; i < 2; ++i) {
    const int s0 = i * 1024 + tid * 4;
    ushort4 xu = *reinterpret_cast<const ushort4*>(xr + s0);
    ushort4 fu = *reinterpret_cast<const ushort4*>(fr + s0);
    xv[i][0] = bf2f(xu.x); xv[i][1] = bf2f(xu.y); xv[i][2] = bf2f(xu.z); xv[i][3] = bf2f(xu.w);
    fv[i][0] = bf2f(fu.x); fv[i][1] = bf2f(fu.y); fv[i][2] = bf2f(fu.z); fv[i][3] = bf2f(fu.w);
    part += xv[i][0] * fv[i][0] + xv[i][1] * fv[i][1] + xv[i][2] * fv[i][2] + xv[i][3] * fv[i][3];
  }
  #pragma unroll
  for (int off = 1; off < 64; off <<= 1) part += __shfl_xor(part, off);
  __shared__ float wsum[4];
  const int wave = tid >> 6, lane = tid & 63;
  if (lane == 0) wsum[wave] = part;
  __syncthreads();
  const float avg = wsum[0] + wsum[1] + wsum[2] + wsum[3];

  #pragma unroll
  for (int i = 0; i < 2; ++i) {
    float4 o;
    o.x = xv[i][0] * (1.f + fv[i][0] - avg); o.x = o.x > 0.f ? o.x : 0.f;
    o.y = xv[i][1] * (1.f + fv[i][1] - avg); o.y = o.y > 0.f ? o.y : 0.f;
    o.z = xv[i][2] * (1.f + fv[i][2] - avg); o.z = o.z > 0.f ? o.z : 0.f;
    o.w = xv[i][3] * (1.f + fv[i][3] - avg); o.w = o.w > 0.f ? o.w : 0.f;
    reinterpret_cast<float4*>(orow)[i * 256 + tid] = o;
  }
}

extern "C" void kernel_launch(void* const* d_in, const int* in_sizes, int n_in,
                              void* d_out, int out_size, void* d_ws, size_t ws_size,
                              hipStream_t stream) {
  const float* x  = (const float*)d_in[0];
  const float* W1 = (const float*)d_in[1];
  const float* W2 = (const float*)d_in[2];
  float* out = (float*)d_out;

  char* ws = (char*)d_ws;
  const size_t nX = (size_t)NBATCH * EMB * SEQ;  // 8,388,608

  size_t off = 0;
  u16* xb   = (u16*)(ws + off); off += nX * 2;                          // 16 MB
  u16* Fcat = (u16*)(ws + off); off += (size_t)NBATCH * SEQ * 1024 * 2; // 32 MB
  const size_t offOverlay = off;                                        // fitb overlays xbT
  u16* xbT  = (u16*)(ws + off); off += nX * 2;                          // 16 MB (dead after D1)
  u16* Wcat = (u16*)(ws + off); off += (size_t)1024 * 512 * 2;          // 1 MB  (dead after D1)
  u16* F2n  = (u16*)(ws + off); off += nX * 2;                          // 16 MB (dead after D2)
  u16* Sd   = (u16*)(ws + off); off += (size_t)NBATCH * 8 * 256 * 256 * 2;  // 8 MB
  u16* Gc   = (u16*)(ws + off); off += (size_t)NBATCH * 8 * EMB * EMB * 2;  // 32 MB
  u16* Gp   = (u16*)(ws + off); off += (size_t)NBATCH * 7 * EMB * EMB * 2;  // 28 MB
  u16* fitb = (u16*)(ws + offOverlay);                                  // 16 MB (over xbT)
  // total: ~149 MiB

  // prep (merged: x tiles on z<8, W1^T on z==8, W2 on z==9)
  prep_kernel<<<dim3(SEQ / 64, EMB / 64, NBATCH + 2), 256, 0, stream>>>(
      x, W1, W2, xb, xbT, Wcat);

  // D1: Fcat + F2n
  k_gemm<0><<<dim3(96, 1, NBATCH), 512, 0, stream>>>(
      xbT, Wcat, nullptr, nullptr, Fcat, F2n);

  // D2: Sd (p0 + p1, long, first) + Gc (short, fills tail round), flat grid
  k_gemm<1><<<dim3(640, 1, 1), 512, 0, stream>>>(
      Fcat, xb, F2n, nullptr, Sd, Gc);

  // D3: prefix-sum chunks -> Gp
  k_prefix<<<dim3(128, 1, NBATCH), 256, 0, stream>>>(Gc, Gp);

  // D4: fitfused -> fitb (bf16), 512 blocks, K-capped diagonal
  k_gemm<2><<<dim3(64, 1, NBATCH), 512, 0, stream>>>(
      Gp, Fcat, xb, Sd, fitb, nullptr);

  // D5: finalize
  finalize_kernel<<<NBATCH * EMB, 256, 0, stream>>>(xb, fitb, out);
}

// Round 16
// 110.313 us; speedup vs baseline: 1.2619x; 1.0343x over previous
//
#include <hip/hip_runtime.h>
#include <hip/hip_bf16.h>
#include <stdint.h>

// ReplicatorDerivLayer on MI355X — factorized causal pipeline, engine v7:
// templated tile width NB (NB=4: 128x256, NB=2: 128x128), BK=32, 3-deep LDS
// (72KB -> 2 blocks/CU), one barrier per K-tile, counted vmcnt, paired-row
// XOR swizzle. This round: F2n comes from a cheap TRANSPOSE of Fcat's F2T
// half (identical values) instead of a duplicate GEMM -> D1 drops 768->512
// blocks = exactly one scheduling round. Engine code untouched (R14 lesson:
// one acc + one pipe body per instantiation; no epilogue surgery).
//
//  prep: x f32 -> xb bf16 [b][e][s] + xbT bf16 [b][s][e]; Wcat=[W1^T;W2] bf16
//  D1: Fcat[s][0:512]=F1T, [512:1024]=F2T   (512 blocks, one round)
//  T:  F2n[b][f][t] = Fcat[b][t][512+f]     (bf16 transpose, 32MB)
//  D2: Sd[b][i] = masked diag Gram (p0 128x128 + p1 128x256);  Gc[b][j]
//  D3: Gp[b][i-1] = sum_{j<i} Gc[b][j]
//  D4: fitb[e, blk i half n2] = Gp_i.F1T^T + xb.Sd^T (K-capped), fused pipe
//  D5: avg = sum_s x*fit; out = relu(x*(1+fit-avg))

#define SEQ 2048
#define EMB 512
#define NBATCH 8

typedef unsigned short u16;
typedef __bf16 bf16x8 __attribute__((ext_vector_type(8)));
typedef float f32x4 __attribute__((ext_vector_type(4)));
typedef u16 u16x8 __attribute__((ext_vector_type(8)));

#define AS1 __attribute__((address_space(1)))
#define AS3 __attribute__((address_space(3)))

#define SBAR do { __builtin_amdgcn_sched_barrier(0); __builtin_amdgcn_s_barrier(); \
                  __builtin_amdgcn_sched_barrier(0); } while (0)
#define LGKM0 do { asm volatile("s_waitcnt lgkmcnt(0)" ::: "memory"); \
                   __builtin_amdgcn_sched_barrier(0); } while (0)
#define VMC(n) asm volatile("s_waitcnt vmcnt(" #n ")" ::: "memory")

__device__ __forceinline__ u16 f2bf(float f) {
  uint32_t u = __builtin_bit_cast(uint32_t, f);
  uint32_t r = u + 0x7FFFu + ((u >> 16) & 1u);
  return (u16)(r >> 16);
}
__device__ __forceinline__ float bf2f(u16 u) {
  return __builtin_bit_cast(float, (uint32_t)u << 16);
}
__device__ __forceinline__ void gld_lds16(const void* g, void* l) {
  __builtin_amdgcn_global_load_lds((AS1 uint32_t*)g, (AS3 uint32_t*)l, 16, 0, 0);
}

// ---------------- merged prep: x -> xb/xbT (z<8); W1^T (z==8); W2 (z==9) ----------------
__global__ __launch_bounds__(256) void prep_kernel(const float* __restrict__ x,
    const float* __restrict__ W1, const float* __restrict__ W2,
    u16* __restrict__ xb, u16* __restrict__ xbT, u16* __restrict__ Wcat) {
  __shared__ float tile[64][65];
  const int tid = threadIdx.x;
  const int z = blockIdx.z;
  if (z < 8) {
    const int b = z;
    const int s0 = blockIdx.x * 64, e0 = blockIdx.y * 64;
    const float* xin = x + (size_t)b * EMB * SEQ;
    #pragma unroll
    for (int it = 0; it < 4; ++it) {
      int idx = it * 256 + tid;
      int r = idx >> 4, c4 = idx & 15;
      float4 v = *(const float4*)(xin + (size_t)(e0 + r) * SEQ + s0 + c4 * 4);
      tile[r][c4 * 4 + 0] = v.x; tile[r][c4 * 4 + 1] = v.y;
      tile[r][c4 * 4 + 2] = v.z; tile[r][c4 * 4 + 3] = v.w;
    }
    __syncthreads();
    u16* ob = xb + (size_t)b * EMB * SEQ;
    #pragma unroll
    for (int it = 0; it < 2; ++it) {
      int idx = it * 256 + tid; int r = idx >> 3, c8 = idx & 7;
      u16x8 o;
      #pragma unroll
      for (int q = 0; q < 8; ++q) o[q] = f2bf(tile[r][c8 * 8 + q]);
      *(u16x8*)(ob + (size_t)(e0 + r) * SEQ + s0 + c8 * 8) = o;
    }
    u16* obT = xbT + (size_t)b * SEQ * EMB;
    #pragma unroll
    for (int it = 0; it < 2; ++it) {
      int idx = it * 256 + tid; int r = idx >> 3, c8 = idx & 7;
      u16x8 o;
      #pragma unroll
      for (int q = 0; q < 8; ++q) o[q] = f2bf(tile[c8 * 8 + q][r]);
      *(u16x8*)(obT + (size_t)(s0 + r) * EMB + e0 + c8 * 8) = o;
    }
  } else {
    const int idx = blockIdx.y * 32 + blockIdx.x;   // 0..255
    const int c0 = (idx & 15) * 32, r0 = (idx >> 4) * 32;
    const int tx = tid & 31, ty = tid >> 5;          // (32, 8)
    if (z == 8) {  // W1^T -> Wcat rows 0..511
      #pragma unroll
      for (int i = 0; i < 32; i += 8)
        tile[ty + i][tx] = W1[(size_t)(r0 + ty + i) * EMB + c0 + tx];
      __syncthreads();
      #pragma unroll
      for (int i = 0; i < 32; i += 8)
        Wcat[(size_t)(c0 + ty + i) * EMB + r0 + tx] = f2bf(tile[tx][ty + i]);
    } else {       // W2 cast -> Wcat rows 512..1023
      u16* W2b = Wcat + (size_t)512 * 512;
      #pragma unroll
      for (int i = 0; i < 32; i += 8)
        W2b[(size_t)(r0 + ty + i) * EMB + c0 + tx] =
            f2bf(W2[(size_t)(r0 + ty + i) * EMB + c0 + tx]);
    }
  }
}

// ---------------- F2n transpose: F2n[b][f][t] = Fcat[b][t][512+f] ----------------
// 64x64 bf16 tiles, ushort4 coalesced loads/stores. grid (32, 8, 8), 256 thr.
__global__ __launch_bounds__(256) void k_t2n(const u16* __restrict__ Fcat,
                                             u16* __restrict__ F2n) {
  __shared__ u16 tile[64][68];   // +4 u16 pad: de-power-of-2 the row stride
  const int b = blockIdx.z;
  const int t0 = blockIdx.x * 64, f0 = blockIdx.y * 64;
  const u16* src = Fcat + (size_t)b * SEQ * 1024 + 512;
  u16* dst = F2n + (size_t)b * EMB * SEQ;
  const int tx = threadIdx.x & 15, ty = threadIdx.x >> 4;  // 16 x 16
  #pragma unroll
  for (int i = 0; i < 64; i += 16) {
    ushort4 v = *(const ushort4*)(src + (size_t)(t0 + ty + i) * 1024 + f0 + tx * 4);
    *(ushort4*)&tile[ty + i][tx * 4] = v;
  }
  __syncthreads();
  #pragma unroll
  for (int i = 0; i < 64; i += 16) {
    ushort4 o;
    o.x = tile[tx * 4 + 0][ty + i];
    o.y = tile[tx * 4 + 1][ty + i];
    o.z = tile[tx * 4 + 2][ty + i];
    o.w = tile[tx * 4 + 3][ty + i];
    *(ushort4*)(dst + (size_t)(f0 + ty + i) * SEQ + t0 + tx * 4) = o;
  }
}

// ---------------- engine v7: 128 x (64*NB) tile, BK=32, 3-deep ----------------
struct Smem {
  __align__(16) u16 A[3][4096];   // 128 rows x 32 cols bf16 (8KB)
  __align__(16) u16 B[3][8192];   // up to 256 rows x 32 cols (16KB; NB2 uses 8KB)
};

// par(t, ab, g, ld, k): operand source for K-tile t (32 cols), ab: 0=A, 1=B.
template<int NB, typename PAR>
__device__ __forceinline__ void gemm_pipe(PAR par, int nk, Smem& sm, f32x4 (&acc)[4][NB]) {
  const int tid = threadIdx.x, lane = tid & 63, wave = tid >> 6;
  const int wr = wave >> 2, wc = wave & 3;      // 2 x 4 waves; per-wave 64 x 16*NB
  const int ar = lane & 15, asel = lane >> 4;

  // LDS: line L (128B) holds rows 2L,2L+1 (4 chunks each);
  // chunk pos within line = ((row&1)*4 | colchunk) ^ (L&7) -> b128 reads conflict-light.
  auto stage = [&](int t) {
    const u16 *ga, *gb; int lda, ldb, ka, kb;
    par(t, 0, ga, lda, ka);
    par(t, 1, gb, ldb, kb);
    u16* LA = sm.A[t % 3];
    u16* LB = sm.B[t % 3];
    {
      int line = tid >> 3, cp = (tid & 7) ^ (line & 7);
      int row = line * 2 + (cp >> 2), cc = cp & 3;
      gld_lds16(ga + (size_t)row * lda + ka + cc * 8, LA + (size_t)(wave * 64) * 8);
    }
    #pragma unroll
    for (int p = 0; p < NB / 2; ++p) {
      int idx = p * 512 + tid;
      int line = idx >> 3, cp = (idx & 7) ^ (line & 7);
      int row = line * 2 + (cp >> 2), cc = cp & 3;
      gld_lds16(gb + (size_t)row * ldb + kb + cc * 8, LB + (size_t)(p * 512 + wave * 64) * 8);
    }
  };
  auto ldfrag = [&](const u16* base, int rloc) -> bf16x8 {
    int line = rloc >> 1;
    int ch = line * 8 + ((((rloc & 1) << 2) | asel) ^ (line & 7));
    return *reinterpret_cast<const bf16x8*>(base + (size_t)ch * 8);
  };

  stage(0);
  if (nk > 1) stage(1);
  if (nk > 1) { if constexpr (NB == 4) { VMC(3); } else { VMC(2); } }
  else        { VMC(0); }
  SBAR;

  for (int t = 0; t < nk; ++t) {
    const u16* A = sm.A[t % 3];
    const u16* B = sm.B[t % 3];
    bf16x8 af[4], bf[NB];
    #pragma unroll
    for (int m = 0; m < 4; ++m) af[m] = ldfrag(A, wr * 64 + m * 16 + ar);
    #pragma unroll
    for (int n = 0; n < NB; ++n) bf[n] = ldfrag(B, wc * (16 * NB) + n * 16 + ar);
    // stage(t+2) targets buf[(t-1)%3]: all waves' reads of it drained before
    // the barrier that ended tile t-1 (LGKM0 precedes that barrier) -> WAR-safe.
    if (t + 2 < nk) stage(t + 2);
    LGKM0;
    __builtin_amdgcn_s_setprio(1);
    #pragma unroll
    for (int m = 0; m < 4; ++m)
      #pragma unroll
      for (int n = 0; n < NB; ++n)
        acc[m][n] = __builtin_amdgcn_mfma_f32_16x16x32_bf16(af[m], bf[n], acc[m][n], 0, 0, 0);
    __builtin_amdgcn_s_setprio(0);
    if (t + 1 < nk) {
      if (t + 2 < nk) { if constexpr (NB == 4) { VMC(3); } else { VMC(2); } }
      else            { VMC(0); }
    }
    SBAR;
  }
}

// ---------------- GEMM kernels ----------------
// MODE 0 grid (64,1,8): Fcat (m=id&15, n=id>>4) [NB4]  (F2n now via k_t2n)
// MODE 1 grid (640,1,1) flat, Sd first so the 128-block tail round is all
//   short Gc blocks: id<64 -> Sd p0 (b=id>>3, i=id&7) [NB2];
//   id<128 -> Sd p1 (b=(id-64)>>3, i=(id-64)&7) [NB4];
//   id>=128 -> Gc (id2=id-128: j=id2&7, b=(id2>>3)&7, sub=id2>>6) [NB4, 8 tiles]
// MODE 2 grid (64,1,8): fitb (i=id&7, m=(id>>3)&3, n2=id>>5) [NB2, K-capped diag]
template<int MODE>
__global__ __launch_bounds__(512, 4) void k_gemm(
    const u16* __restrict__ X1, const u16* __restrict__ X2,
    const u16* __restrict__ X3, const u16* __restrict__ X4,
    u16* __restrict__ O16, u16* __restrict__ O16b) {
  __shared__ Smem sm;
  const int tid  = threadIdx.x;
  const int lane = tid & 63;
  const int wave = tid >> 6;
  const int wr = wave >> 2;
  const int wc = wave & 3;
  const int bz = blockIdx.z;
  const int id = blockIdx.x;

  const int r0 = (lane >> 4) * 4;
  const int cn = lane & 15;

  if (MODE == 0) {
    const int m = id & 15, n = id >> 4;
    const u16* Ap = X1 + (size_t)bz * SEQ * EMB + (size_t)(m * 128) * 512;
    const u16* Bp = X2 + (size_t)(n * 256) * 512;
    auto par = [&](int t, int ab, const u16*& gp, int& ld, int& k) {
      gp = ab ? Bp : Ap; ld = 512; k = t * 32;
    };
    f32x4 acc[4][4];
    #pragma unroll
    for (int i = 0; i < 4; ++i)
      #pragma unroll
      for (int j = 0; j < 4; ++j) acc[i][j] = (f32x4){0.f, 0.f, 0.f, 0.f};
    gemm_pipe<4>(par, 16, sm, acc);
    u16* C = O16 + (size_t)bz * SEQ * 1024;
    #pragma unroll
    for (int mm = 0; mm < 4; ++mm)
      #pragma unroll
      for (int nn = 0; nn < 4; ++nn)
        #pragma unroll
        for (int r = 0; r < 4; ++r) {
          int lr = wr * 64 + mm * 16 + r0 + r, lc = wc * 64 + nn * 16 + cn;
          C[(size_t)(m * 128 + lr) * 1024 + n * 256 + lc] = f2bf(acc[mm][nn][r]);
        }
  } else if (MODE == 1) {
    if (id < 64) {     // Sd p0: 128x128 lower quadrant, NB2, K=512
      const int b = id >> 3, i = id & 7;
      const u16* Fb = X1 + (size_t)b * SEQ * 1024;
      const u16* Ap = Fb + (size_t)(i * 256) * 1024;
      const u16* Bp = Fb + 512 + (size_t)(i * 256) * 1024;
      auto par = [&](int t, int ab, const u16*& gp, int& ld, int& k) {
        gp = ab ? Bp : Ap; ld = 1024; k = t * 32;
      };
      f32x4 acc[4][2];
      #pragma unroll
      for (int a = 0; a < 4; ++a)
        #pragma unroll
        for (int c = 0; c < 2; ++c) acc[a][c] = (f32x4){0.f, 0.f, 0.f, 0.f};
      gemm_pipe<2>(par, 16, sm, acc);
      u16* C = O16 + (size_t)(b * 8 + i) * 256 * 256;
      #pragma unroll
      for (int mm = 0; mm < 4; ++mm)
        #pragma unroll
        for (int nn = 0; nn < 2; ++nn)
          #pragma unroll
          for (int r = 0; r < 4; ++r) {
            int lr = wr * 64 + mm * 16 + r0 + r, lc = wc * 32 + nn * 16 + cn;
            float v = (lc > lr) ? 0.f : acc[mm][nn][r];  // keep t <= s
            C[(size_t)lr * 256 + lc] = f2bf(v);
          }
    } else if (id < 128) {  // Sd p1: rows 128-255 full width, NB4, K=512
      const int id2 = id - 64, b = id2 >> 3, i = id2 & 7;
      const u16* Fb = X1 + (size_t)b * SEQ * 1024;
      const u16* Ap = Fb + (size_t)(i * 256 + 128) * 1024;
      const u16* Bp = Fb + 512 + (size_t)(i * 256) * 1024;
      auto par = [&](int t, int ab, const u16*& gp, int& ld, int& k) {
        gp = ab ? Bp : Ap; ld = 1024; k = t * 32;
      };
      f32x4 acc[4][4];
      #pragma unroll
      for (int a = 0; a < 4; ++a)
        #pragma unroll
        for (int c = 0; c < 4; ++c) acc[a][c] = (f32x4){0.f, 0.f, 0.f, 0.f};
      gemm_pipe<4>(par, 16, sm, acc);
      u16* C = O16 + (size_t)(b * 8 + i) * 256 * 256;
      #pragma unroll
      for (int mm = 0; mm < 4; ++mm)
        #pragma unroll
        for (int nn = 0; nn < 4; ++nn)
          #pragma unroll
          for (int r = 0; r < 4; ++r) {
            int lr = wr * 64 + mm * 16 + r0 + r, lc = wc * 64 + nn * 16 + cn;
            int grow = 128 + lr;
            float v = (lc > grow) ? 0.f : acc[mm][nn][r];
            C[(size_t)grow * 256 + lc] = f2bf(v);
          }
    } else {           // Gc (j; m,n): NB4, K=256 (short: fills the tail round)
      const int id2 = id - 128;
      const int j = id2 & 7, b = (id2 >> 3) & 7, sub = id2 >> 6;
      const int m = sub >> 1, n = sub & 1;
      const u16* Ap = X2 + (size_t)b * EMB * SEQ + (size_t)(m * 128) * SEQ + j * 256;
      const u16* Bp = X3 + (size_t)b * EMB * SEQ + (size_t)(n * 256) * SEQ + j * 256;
      auto par = [&](int t, int ab, const u16*& gp, int& ld, int& k) {
        gp = ab ? Bp : Ap; ld = SEQ; k = t * 32;
      };
      f32x4 acc[4][4];
      #pragma unroll
      for (int a = 0; a < 4; ++a)
        #pragma unroll
        for (int c = 0; c < 4; ++c) acc[a][c] = (f32x4){0.f, 0.f, 0.f, 0.f};
      gemm_pipe<4>(par, 8, sm, acc);
      u16* C = O16b + (size_t)(b * 8 + j) * EMB * EMB;
      #pragma unroll
      for (int mm = 0; mm < 4; ++mm)
        #pragma unroll
        for (int nn = 0; nn < 4; ++nn)
          #pragma unroll
          for (int r = 0; r < 4; ++r) {
            int lr = wr * 64 + mm * 16 + r0 + r, lc = wc * 64 + nn * 16 + cn;
            C[(size_t)(m * 128 + lr) * EMB + n * 256 + lc] = f2bf(acc[mm][nn][r]);
          }
    }
  } else {
    // fitfused NB2: i = id&7 (s-block), m = (id>>3)&3 (e-quarter), n2 = id>>5 (s-half)
    // tiles 0-15: Gp_i . F1T^T (K=512); then diag: K = n2 ? 256 : 128 (t <= s cap)
    const int i = id & 7, m = (id >> 3) & 3, n2 = id >> 5;
    const u16* Agp = (i > 0) ? X1 + (size_t)(bz * 7 + i - 1) * EMB * EMB + (size_t)(m * 128) * 512
                             : X1;
    const u16* Bf1 = X2 + (size_t)bz * SEQ * 1024 + (size_t)(i * 256 + n2 * 128) * 1024;
    const u16* Axb = X3 + (size_t)bz * EMB * SEQ + (size_t)(m * 128) * SEQ;
    const u16* Bsd = X4 + (size_t)(bz * 8 + i) * 256 * 256 + (size_t)(n2 * 128) * 256;
    auto par = [&](int t, int ab, const u16*& gp, int& ld, int& k) {
      int tt = (i > 0) ? t : t + 16;
      if (tt < 16) {
        if (!ab) { gp = Agp; ld = 512;  k = tt * 32; }
        else     { gp = Bf1; ld = 1024; k = tt * 32; }
      } else {
        int u = tt - 16;
        if (!ab) { gp = Axb; ld = SEQ; k = i * 256 + u * 32; }
        else     { gp = Bsd; ld = 256; k = u * 32; }
      }
    };
    const int nkd = n2 ? 8 : 4;
    f32x4 acc[4][2];
    #pragma unroll
    for (int a = 0; a < 4; ++a)
      #pragma unroll
      for (int c = 0; c < 2; ++c) acc[a][c] = (f32x4){0.f, 0.f, 0.f, 0.f};
    gemm_pipe<2>(par, (i > 0 ? 16 : 0) + nkd, sm, acc);
    u16* C = O16 + (size_t)bz * EMB * SEQ;
    #pragma unroll
    for (int mm = 0; mm < 4; ++mm)
      #pragma unroll
      for (int nn = 0; nn < 2; ++nn)
        #pragma unroll
        for (int r = 0; r < 4; ++r) {
          int lr = wr * 64 + mm * 16 + r0 + r, lc = wc * 32 + nn * 16 + cn;
          C[(size_t)(m * 128 + lr) * SEQ + i * 256 + n2 * 128 + lc] = f2bf(acc[mm][nn][r]);
        }
  }
}

// ---------------- prefix over chunks: Gp[b][i-1] = sum_{j<i} Gc[b][j] ----------------
__global__ __launch_bounds__(256) void k_prefix(const u16* __restrict__ Gc,
                                                u16* __restrict__ Gp) {
  const int b = blockIdx.z;
  const size_t base = ((size_t)blockIdx.x * 256 + threadIdx.x) * 8;
  float run[8] = {0.f, 0.f, 0.f, 0.f, 0.f, 0.f, 0.f, 0.f};
  #pragma unroll
  for (int j = 0; j < 7; ++j) {
    u16x8 v = *(const u16x8*)(Gc + (size_t)(b * 8 + j) * EMB * EMB + base);
    u16x8 o;
    #pragma unroll
    for (int q = 0; q < 8; ++q) { run[q] += bf2f(v[q]); o[q] = f2bf(run[q]); }
    *(u16x8*)(Gp + (size_t)(b * 7 + j) * EMB * EMB + base) = o;
  }
}

// ---------------- finalize (fit in bf16) ----------------
__global__ __launch_bounds__(256) void finalize_kernel(const u16* __restrict__ xb,
    const u16* __restrict__ fitb, float* __restrict__ out) {
  const size_t row = blockIdx.x;  // b*EMB + e
  const u16* xr = xb + row * SEQ;
  const u16* fr = fitb + row * SEQ;
  float* orow = out + row * SEQ;
  const int tid = threadIdx.x;

  float xv[2][4], fv[2][4];
  float part = 0.f;
  #pragma unroll
  for (int i = 0; i < 2; ++i) {
    const int s0 = i * 1024 + tid * 4;
    ushort4 xu = *reinterpret_cast<const ushort4*>(xr + s0);
    ushort4 fu = *reinterpret_cast<const ushort4*>(fr + s0);
    xv[i][0] = bf2f(xu.x); xv[i][1] = bf2f(xu.y); xv[i][2] = bf2f(xu.z); xv[i][3] = bf2f(xu.w);
    fv[i][0] = bf2f(fu.x); fv[i][1] = bf2f(fu.y); fv[i][2] = bf2f(fu.z); fv[i][3] = bf2f(fu.w);
    part += xv[i][0] * fv[i][0] + xv[i][1] * fv[i][1] + xv[i][2] * fv[i][2] + xv[i][3] * fv[i][3];
  }
  #pragma unroll
  for (int off = 1; off < 64; off <<= 1) part += __shfl_xor(part, off);
  __shared__ float wsum[4];
  const int wave = tid >> 6, lane = tid & 63;
  if (lane == 0) wsum[wave] = part;
  __syncthreads();
  const float avg = wsum[0] + wsum[1] + wsum[2] + wsum[3];

  #pragma unroll
  for (int i = 0; i < 2; ++i) {
    float4 o;
    o.x = xv[i][0] * (1.f + fv[i][0] - avg); o.x = o.x > 0.f ? o.x : 0.f;
    o.y = xv[i][1] * (1.f + fv[i][1] - avg); o.y = o.y > 0.f ? o.y : 0.f;
    o.z = xv[i][2] * (1.f + fv[i][2] - avg); o.z = o.z > 0.f ? o.z : 0.f;
    o.w = xv[i][3] * (1.f + fv[i][3] - avg); o.w = o.w > 0.f ? o.w : 0.f;
    reinterpret_cast<float4*>(orow)[i * 256 + tid] = o;
  }
}

extern "C" void kernel_launch(void* const* d_in, const int* in_sizes, int n_in,
                              void* d_out, int out_size, void* d_ws, size_t ws_size,
                              hipStream_t stream) {
  const float* x  = (const float*)d_in[0];
  const float* W1 = (const float*)d_in[1];
  const float* W2 = (const float*)d_in[2];
  float* out = (float*)d_out;

  char* ws = (char*)d_ws;
  const size_t nX = (size_t)NBATCH * EMB * SEQ;  // 8,388,608

  size_t off = 0;
  u16* xb   = (u16*)(ws + off); off += nX * 2;                          // 16 MB
  u16* Fcat = (u16*)(ws + off); off += (size_t)NBATCH * SEQ * 1024 * 2; // 32 MB
  const size_t offOverlay = off;                                        // fitb overlays xbT
  u16* xbT  = (u16*)(ws + off); off += nX * 2;                          // 16 MB (dead after D1)
  u16* Wcat = (u16*)(ws + off); off += (size_t)1024 * 512 * 2;          // 1 MB  (dead after D1)
  u16* F2n  = (u16*)(ws + off); off += nX * 2;                          // 16 MB (dead after D2)
  u16* Sd   = (u16*)(ws + off); off += (size_t)NBATCH * 8 * 256 * 256 * 2;  // 8 MB
  u16* Gc   = (u16*)(ws + off); off += (size_t)NBATCH * 8 * EMB * EMB * 2;  // 32 MB
  u16* Gp   = (u16*)(ws + off); off += (size_t)NBATCH * 7 * EMB * EMB * 2;  // 28 MB
  u16* fitb = (u16*)(ws + offOverlay);                                  // 16 MB (over xbT)
  // total: ~149 MiB

  // prep (merged: x tiles on z<8, W1^T on z==8, W2 on z==9)
  prep_kernel<<<dim3(SEQ / 64, EMB / 64, NBATCH + 2), 256, 0, stream>>>(
      x, W1, W2, xb, xbT, Wcat);

  // D1: Fcat only — 512 blocks = one scheduling round
  k_gemm<0><<<dim3(64, 1, NBATCH), 512, 0, stream>>>(
      xbT, Wcat, nullptr, nullptr, Fcat, nullptr);

  // T: F2n = transpose of Fcat's F2T half (identical values, no recompute)
  k_t2n<<<dim3(32, 8, NBATCH), 256, 0, stream>>>(Fcat, F2n);

  // D2: Sd (p0 + p1, long, first) + Gc (short, fills tail round), flat grid
  k_gemm<1><<<dim3(640, 1, 1), 512, 0, stream>>>(
      Fcat, xb, F2n, nullptr, Sd, Gc);

  // D3: prefix-sum chunks -> Gp
  k_prefix<<<dim3(128, 1, NBATCH), 256, 0, stream>>>(Gc, Gp);

  // D4: fitfused -> fitb (bf16), 512 blocks, K-capped diagonal
  k_gemm<2><<<dim3(64, 1, NBATCH), 512, 0, stream>>>(
      Gp, Fcat, xb, Sd, fitb, nullptr);

  // D5: finalize
  finalize_kernel<<<NBATCH * EMB, 256, 0, stream>>>(xb, fitb, out);
}